// Round 9
// baseline (5121.507 us; speedup 1.0000x reference)
//
#include <hip/hip_runtime.h>

typedef unsigned short u16;
typedef unsigned int u32;
typedef __attribute__((ext_vector_type(8))) short bf16x8;
typedef __attribute__((ext_vector_type(4))) float f32x4;

__device__ __forceinline__ float b2f(u16 u) { return __uint_as_float(((u32)u) << 16); }
__device__ __forceinline__ u16 f2b(float f) {
  u32 u = __float_as_uint(f);
  return (u16)((u + 0x7FFFu + ((u >> 16) & 1u)) >> 16);
}

__device__ __forceinline__ void gld_lds16(const void* g, void* l) {
  __builtin_amdgcn_global_load_lds((const __attribute__((address_space(1))) u32*)g,
                                   (__attribute__((address_space(3))) u32*)l, 16, 0, 0);
}

// ---------------- adp = softmax(relu(nv1@nv2), axis=1), bf16, row-major (v,w) ----------------
__global__ __launch_bounds__(256) void k_adp(const float* __restrict__ nv1,
                                             const float* __restrict__ nv2,
                                             u16* __restrict__ adp) {
  int v = blockIdx.x, t = threadIdx.x;
  __shared__ float red[8];
  const float* nrow = nv1 + v * 10;
  float z[4];
#pragma unroll
  for (int j = 0; j < 4; j++) {
    int w = t + j * 256;
    float s = 0.f;
#pragma unroll
    for (int a = 0; a < 10; a++) s += nrow[a] * nv2[a * 1024 + w];
    z[j] = fmaxf(s, 0.f);
  }
  float m = fmaxf(fmaxf(z[0], z[1]), fmaxf(z[2], z[3]));
  for (int off = 32; off; off >>= 1) m = fmaxf(m, __shfl_down(m, off));
  if ((t & 63) == 0) red[t >> 6] = m;
  __syncthreads();
  m = fmaxf(fmaxf(red[0], red[1]), fmaxf(red[2], red[3]));
  float e[4], s = 0.f;
#pragma unroll
  for (int j = 0; j < 4; j++) { e[j] = __expf(z[j] - m); s += e[j]; }
  for (int off = 32; off; off >>= 1) s += __shfl_down(s, off);
  if ((t & 63) == 0) red[4 + (t >> 6)] = s;
  __syncthreads();
  s = red[4] + red[5] + red[6] + red[7];
  float inv = 1.0f / s;
#pragma unroll
  for (int j = 0; j < 4; j++) adp[(long)v * 1024 + t + j * 256] = f2b(e[j] * inv);
}

// ---------------- transpose 1024x1024 bf16 ----------------
__global__ __launch_bounds__(256) void k_transpose(const u16* __restrict__ in, u16* __restrict__ out) {
  __shared__ u16 tile[64 * 65];
  int w0 = blockIdx.x * 64, v0 = blockIdx.y * 64, t = threadIdx.x;
  int c = t & 63, r4 = t >> 6;
  for (int rr = r4; rr < 64; rr += 4) tile[rr * 65 + c] = in[(long)(v0 + rr) * 1024 + w0 + c];
  __syncthreads();
  for (int rr = r4; rr < 64; rr += 4) out[(long)(w0 + rr) * 1024 + v0 + c] = tile[c * 65 + rr];
}

// ---------------- pack bcatT: [k/8][n][8] granule-major for coalesced B-fragment loads ----------
// n = (v>>6)*128 + src*64 + (v&63); K-granule order preserved -> bit-identical accumulation.
__global__ __launch_bounds__(256) void k_pack(const u16* __restrict__ adpT, const u16* __restrict__ adp2T,
                                              u16* __restrict__ bcatT) {
  int n = blockIdx.x;
  int g = n >> 7, rem = n & 127, src = rem >> 6, v = g * 64 + (rem & 63);
  const u16* s = (src ? adp2T : adpT) + (long)v * 1024;
  int t = threadIdx.x;
  ushort4 val = ((const ushort4*)s)[t];
  *(ushort4*)(bcatT + (long)(t >> 1) * 16384 + n * 8 + (t & 1) * 4) = val;
}

// ---------------- weight repacks + summed skip bias ----------------
__global__ __launch_bounds__(256) void k_wprep(const float* __restrict__ skw, const float* __restrict__ skb,
                                               const float* __restrict__ e1w,
                                               const float* __restrict__ fw, const float* __restrict__ gw,
                                               const float* __restrict__ gcw,
                                               u16* __restrict__ wcat, u16* __restrict__ e1bf,
                                               float* __restrict__ sbias,
                                               u16* __restrict__ fwgB, u16* __restrict__ gcwB) {
  int idx = blockIdx.x * 256 + threadIdx.x;
  if (idx < 65536) {
    int cp = idx >> 8, k = idx & 255, i = k >> 5, c = k & 31;
    wcat[idx] = f2b(skw[(i * 256 + cp) * 32 + c]);
  } else if (idx < 196608) {
    int j = idx - 65536;
    e1bf[j] = f2b(e1w[j]);
  } else if (idx < 229376) {
    int j = idx - 196608;
    int layer = j >> 12, rem = j & 4095, n = rem >> 6, k = rem & 63;
    int tap = k >> 5, ci = k & 31, oc = n & 31;
    const float* src = (n < 32) ? fw : gw;
    fwgB[j] = f2b(src[((layer * 32 + oc) * 32 + ci) * 2 + tap]);
  } else if (idx < 253952) {
    int j = idx - 229376;  // native-order bf16 copy of gc_w
    gcwB[j] = f2b(gcw[j]);
  }
  if (idx < 256) {
    float s = 0.f;
    for (int i = 0; i < 8; i++) s += skb[i * 256 + idx];
    sbias[idx] = s;
  }
}

// ---------------- start conv: h[b][slot][v][c] bf16 ----------------
__global__ __launch_bounds__(256) void k_start(const float* __restrict__ x, const float* __restrict__ sw,
                                               const float* __restrict__ sb, u16* __restrict__ h, int b0) {
  int bl = blockIdx.y, bg = b0 + bl, v0 = blockIdx.x * 64, t = threadIdx.x;
  __shared__ float xs[2 * 832];  // [i][vl*13+l]
  for (int idx = t; idx < 2 * 832; idx += 256) {
    int i = idx / 832, rem = idx % 832;
    xs[idx] = x[((long)(bg * 2 + i) * 1024 + v0) * 13 + rem];
  }
  __syncthreads();
  for (int p = t; p < 832; p += 256) {
    int l = p % 13, vl = p / 13;
    float x0 = xs[vl * 13 + l];
    float x1 = xs[832 + vl * 13 + l];
    u16* dst = h + ((long)(bl * 13 + l) * 1024 + v0 + vl) * 32;
#pragma unroll
    for (int cq = 0; cq < 4; cq++) {
      bf16x8 pk;
#pragma unroll
      for (int j = 0; j < 8; j++) {
        int c = cq * 8 + j;
        pk[j] = (short)f2b(sw[c * 2 + 0] * x0 + sw[c * 2 + 1] * x1 + sb[c]);
      }
      *(bf16x8*)(dst + cq * 8) = pk;
    }
  }
}

// ---------------- gated dilated conv via MFMA: M=v, N=64 (f|g), K=64 (2 taps x 32 ci) ----------
__global__ __launch_bounds__(256, 2) void k_gate(const u16* __restrict__ h, u16* __restrict__ hg,
                                                 u16* __restrict__ hlast,
                                                 const u16* __restrict__ fwgB,
                                                 const float* __restrict__ fb, const float* __restrict__ gb,
                                                 int Lo, int d, int off, int layer, int writehg) {
  int t = threadIdx.x, wave = t >> 6, lane = t & 63;
  int q = lane >> 4, r = lane & 15;
  int b = blockIdx.z, l = blockIdx.y;
  int vbase = blockIdx.x * 256 + wave * 64;
  f32x4 acc[4][4] = {};
  const u16* wb = fwgB + layer * 4096;
#pragma unroll
  for (int ks = 0; ks < 2; ks++) {
    const u16* hrow = h + ((long)(b * 13 + off + l + ks * d) * 1024) * 32;
    bf16x8 af[4], bf[4];
#pragma unroll
    for (int mt = 0; mt < 4; mt++)
      af[mt] = *(const bf16x8*)(hrow + (long)(vbase + mt * 16 + r) * 32 + q * 8);
#pragma unroll
    for (int nt = 0; nt < 4; nt++)
      bf[nt] = *(const bf16x8*)(wb + (nt * 16 + r) * 64 + ks * 32 + q * 8);
#pragma unroll
    for (int mt = 0; mt < 4; mt++)
#pragma unroll
      for (int nt = 0; nt < 4; nt++)
        acc[mt][nt] = __builtin_amdgcn_mfma_f32_16x16x32_bf16(af[mt], bf[nt], acc[mt][nt], 0, 0, 0);
  }
  int last = (l == Lo - 1);
#pragma unroll
  for (int nt = 0; nt < 2; nt++) {
    int oc = nt * 16 + r;
    float fbv = fb[layer * 32 + oc], gbv = gb[layer * 32 + oc];
#pragma unroll
    for (int mt = 0; mt < 4; mt++) {
      u16 vv[4];
#pragma unroll
      for (int rg = 0; rg < 4; rg++) {
        float f = acc[mt][nt][rg] + fbv;
        float g = acc[mt][nt + 2][rg] + gbv;
        float ft = 2.f * __builtin_amdgcn_rcpf(1.f + __expf(-2.f * f)) - 1.f;
        float sg = __builtin_amdgcn_rcpf(1.f + __expf(-g));
        vv[rg] = f2b(ft * sg);
      }
      int v0 = vbase + mt * 16 + q * 4;
      if (writehg) {
        ushort4 pk; pk.x = vv[0]; pk.y = vv[1]; pk.z = vv[2]; pk.w = vv[3];
        *(ushort4*)(hg + ((long)(b * Lo + l) * 32 + oc) * 1024 + v0) = pk;
      }
      if (last) {
#pragma unroll
        for (int rg = 0; rg < 4; rg++)
          hlast[((long)(b * 1024 + v0 + rg)) * 256 + layer * 32 + oc] = vv[rg];
      }
    }
  }
}

// ---------------- generic GEMM (m97 structure), used for adp2 + end-head ----------------
__global__ __launch_bounds__(256) void k_gemm(const u16* __restrict__ A, const u16* __restrict__ Bt,
                                              u16* __restrict__ C, int M, int N, int K,
                                              const float* __restrict__ bias, int relu) {
  __shared__ __align__(16) u16 As[128 * 32];
  __shared__ __align__(16) u16 Bs[128 * 32];
  int t = threadIdx.x, wave = t >> 6, lane = t & 63;
  int m0 = blockIdx.y * 128, n0 = blockIdx.x * 128;
  int wr = (wave >> 1) * 64, wc = (wave & 1) * 64;
  int q = lane >> 4, r = lane & 15;
  f32x4 acc[4][4] = {};
  const u16* Ag = A + (long)(m0 + wave * 32 + (lane >> 2)) * K + (lane & 3) * 8;
  const u16* Bg = Bt + (long)(n0 + wave * 32 + (lane >> 2)) * K + (lane & 3) * 8;
  u16* Al = As + wave * 1024 + lane * 8;
  u16* Bl = Bs + wave * 1024 + lane * 8;
  for (int k0 = 0; k0 < K; k0 += 32) {
    __syncthreads();
    gld_lds16(Ag + k0, Al);
    gld_lds16(Ag + 16 * K + k0, Al + 512);
    gld_lds16(Bg + k0, Bl);
    gld_lds16(Bg + 16 * K + k0, Bl + 512);
    __syncthreads();
    bf16x8 af[4], bfr[4];
#pragma unroll
    for (int i = 0; i < 4; i++) {
      af[i] = *(const bf16x8*)(As + (wr + i * 16 + r) * 32 + q * 8);
      bfr[i] = *(const bf16x8*)(Bs + (wc + i * 16 + r) * 32 + q * 8);
    }
#pragma unroll
    for (int i = 0; i < 4; i++)
#pragma unroll
      for (int j = 0; j < 4; j++)
        acc[i][j] = __builtin_amdgcn_mfma_f32_16x16x32_bf16(af[i], bfr[j], acc[i][j], 0, 0, 0);
  }
#pragma unroll
  for (int i = 0; i < 4; i++) {
    int row = m0 + wr + i * 16 + q * 4;
#pragma unroll
    for (int j = 0; j < 4; j++) {
      int col = n0 + wc + j * 16 + r;
      float bv = bias ? bias[col] : 0.f;
#pragma unroll
      for (int rg = 0; rg < 4; rg++) {
        float vv = acc[i][j][rg] + bv;
        if (relu) vv = fmaxf(vv, 0.f);
        C[(long)(row + rg) * N + col] = f2b(vv);
      }
    }
  }
}

// ---------------- FUSED xgc v8: v6 loop (best, 882us) + 40KB LDS -> 4 blocks/CU ---------------
// v7 post-mortem: BK=64 neutral -> not barrier-quantum-bound. The binder is OCCUPANCY: LDS
// 69632B (xcs [256][136] epilogue buffer) caps at 2 blocks/CU = 2 waves/SIMD; VGPR (92) would
// allow 4. At 2 waves/SIMD the per-wave serial chain (lgkm -> 8 ds_read -> 32 MFMA -> barrier)
// yields ~42% MFMA duty. v8: split the xcs transpose into two 128-col halves (34KB). Half hh2
// is written by waves 2*hh2,2*hh2+1 (col_n = wave*64+j*16+r) and consumed exactly by the
// mini-GEMM hh = hh2 pass -> per-accumulator op order unchanged (bit-identical). smem =
// max(loop 16KB, hgT 40KB, xcs-half 34KB) = 40960B -> 4 blocks/CU = 4 waves/SIMD.
#define PADX 136
__global__ __launch_bounds__(256, 4) void k_xgc(const u16* __restrict__ hg, const u16* __restrict__ bcatT,
                                                u16* __restrict__ h,
                                                const u16* __restrict__ gcwB, const float* __restrict__ gcb,
                                                const float* __restrict__ bng, const float* __restrict__ bnb,
                                                int Lo, int d, int off, int layer) {
  // loop: A dbuf [2][128][32] u16 @ [0, 8192)
  // epilogue overlay: hgT 4*5120 = [0, 20480); xcs-half [128][136] = [0, 17408)
  __shared__ __align__(16) u16 smem[20480];
  int t = threadIdx.x, wave = t >> 6, lane = t & 63;
  int q = lane >> 4, r = lane & 15;
  // ---- block-ID remap: super-tile of 8 m-blocks x 8 n-groups -> 2MB A panel L2-resident ----
  int X = gridDim.x;
  int mblk, g;
  if ((X & 7) == 0) {
    int lin = blockIdx.x + X * blockIdx.y;
    mblk = (lin >> 6) * 8 + (lin & 7);
    g = (lin >> 3) & 7;
  } else {
    mblk = blockIdx.x;
    g = blockIdx.y;
  }
  int m0 = mblk * 128, n0 = g * 256;
  // A staging: source granule pre-swizzled (dest linear) so LDS(row,qs) holds granule qs^((row>>1)&3)
  const u16* AgS = hg + (long)(m0 + wave * 32 + (lane >> 2)) * 1024 +
                   (((lane & 3) ^ ((lane >> 3) & 3)) * 8);
  u16* Al = smem + wave * 1024 + lane * 8;
  // B direct: bcatT[(kg)*2048*8 + n*8]; wave n-range = n0 + wave*64
  const u16* BgW = bcatT + (long)(n0 + wave * 64 + r) * 8;
  int qs = (q ^ ((r >> 1) & 3)) * 8;  // swizzled read granule offset (u16)

#define STGA(BUF, K0)                              \
  gld_lds16(AgS + (K0), Al + (BUF) * 4096);        \
  gld_lds16(AgS + 16 * 1024 + (K0), Al + (BUF) * 4096 + 512);

#define LDB(DST, KG)                                                                   \
  _Pragma("unroll") for (int nt = 0; nt < 4; nt++)                                     \
      DST[nt] = *(const bf16x8*)(BgW + ((long)((KG) + q)) * 16384 + nt * 128);

#define MMS(BUF, BF)                                                                   \
  {                                                                                    \
    const u16* Ab = smem + (BUF) * 4096;                                               \
    __builtin_amdgcn_s_setprio(1);                                                     \
    _Pragma("unroll") for (int mt = 0; mt < 8; mt++) {                                 \
      bf16x8 a = *(const bf16x8*)(Ab + (mt * 16 + r) * 32 + qs);                       \
      _Pragma("unroll") for (int nt = 0; nt < 4; nt++)                                 \
          acc[mt][nt] = __builtin_amdgcn_mfma_f32_16x16x32_bf16(a, BF[nt],             \
                                                               acc[mt][nt], 0, 0, 0); \
    }                                                                                  \
    __builtin_amdgcn_s_setprio(0);                                                     \
  }

  f32x4 acc[8][4] = {};
  bf16x8 bA[4], bB[4];

  // prologue: stage A buf0 (k=0), load B k-step 0 into regs
  STGA(0, 0)
  LDB(bA, 0)
  __syncthreads();

#pragma unroll 1
  for (int ix = 0; ix < 16; ++ix) {
    int s1 = 2 * ix + 1, s2 = 2 * ix + 2;
    // even K-step 2ix: prefetch next B + stage buf1
    LDB(bB, s1 * 4)
    STGA(1, s1 * 32)
    MMS(0, bA)
    __syncthreads();
    // odd K-step 2ix+1
    if (s2 < 32) {
      LDB(bA, s2 * 4)
      STGA(0, s2 * 32)
    }
    MMS(1, bB)
    __syncthreads();
  }
#undef STGA
#undef LDB
#undef MMS
  // ---- phase A: stage hg tile transposed: hgT[bl 0..3][w 0..127][ci 0..31], row stride 40 ----
  {
    int row = t >> 1, half = t & 1;
    int bl_ = row >> 5, ci = row & 31;
    const u16* src = hg + (long)(m0 + row) * 1024 + g * 128 + half * 64;
    u16* dstb = smem + bl_ * 5120 + ci;
#pragma unroll
    for (int e = 0; e < 8; e++) {
      bf16x8 v8 = *(const bf16x8*)(src + e * 8);
#pragma unroll
      for (int jj = 0; jj < 8; jj++) dstb[(half * 64 + e * 8 + jj) * 40] = (u16)v8[jj];
    }
  }
  __syncthreads();
  bf16x8 miniA[2][4];
#pragma unroll
  for (int hh = 0; hh < 2; hh++)
#pragma unroll
    for (int wt = 0; wt < 4; wt++)
      miniA[hh][wt] = *(const bf16x8*)(smem + wave * 5120 + (hh * 64 + wt * 16 + r) * 40 + q * 8);
  __syncthreads();  // hgT dead
  // ---- load gc weights once ----
  bf16x8 bf2[2][3];
#pragma unroll
  for (int oct = 0; oct < 2; oct++)
#pragma unroll
    for (int ks = 0; ks < 3; ks++)
      bf2[oct][ks] = *(const bf16x8*)(gcwB + ((long)layer * 32 + oct * 16 + r) * 96 + ks * 32 + q * 8);
  f32x4 acc2[2][4][2] = {};  // [hh][wt][oct]; lane: oc = oct*16+q*4+rg, w = hh*64+wt*16+r
  // ---- two half-passes: write xcs half (128 cols, 34KB), consume via mini-GEMM hh=hh2 ----
#pragma unroll
  for (int hh2 = 0; hh2 < 2; hh2++) {
    if ((wave >> 1) == hh2) {  // waves owning col_n in [hh2*128, hh2*128+128)
#pragma unroll
      for (int i = 0; i < 8; i++) {
#pragma unroll
        for (int j = 0; j < 4; j++) {
          int row_m = i * 16 + q * 4;
          int col_l = (wave & 1) * 64 + j * 16 + r;
          ushort4 pk;
          pk.x = f2b(acc[i][j][0]); pk.y = f2b(acc[i][j][1]);
          pk.z = f2b(acc[i][j][2]); pk.w = f2b(acc[i][j][3]);
          *(ushort4*)(smem + col_l * PADX + row_m) = pk;
        }
      }
    }
    __syncthreads();
    // mini-GEMM hh=hh2 (all waves): a2 within-half n index = (ks-1)*64 + wt*16 + r
#pragma unroll
    for (int wt = 0; wt < 4; wt++) {
#pragma unroll
      for (int oct = 0; oct < 2; oct++)
        acc2[hh2][wt][oct] = __builtin_amdgcn_mfma_f32_16x16x32_bf16(bf2[oct][0], miniA[hh2][wt],
                                                                     acc2[hh2][wt][oct], 0, 0, 0);
#pragma unroll
      for (int ks = 1; ks < 3; ks++) {
        bf16x8 a2 = *(const bf16x8*)(smem + ((ks - 1) * 64 + wt * 16 + r) * PADX +
                                     wave * 32 + q * 8);
#pragma unroll
        for (int oct = 0; oct < 2; oct++)
          acc2[hh2][wt][oct] = __builtin_amdgcn_mfma_f32_16x16x32_bf16(bf2[oct][ks], a2,
                                                                       acc2[hh2][wt][oct], 0, 0, 0);
      }
    }
    __syncthreads();  // xcs-half dead before next half overwrites
  }
  // ---- epilogue: + gcb, residual, BN, in-place h write — ushort4 RMW (4 oc per lane) ----
  int blg = mblk * 4 + wave;
  int b = blg / Lo, l = blg % Lo;
  const float rs = rsqrtf(1.f + 1e-5f);
  u16* hbase = h + ((long)(b * 13 + off + l + d) * 1024 + g * 128) * 32;
#pragma unroll
  for (int oct = 0; oct < 2; oct++) {
    int oc0 = oct * 16 + q * 4;
    float4 g4 = *(const float4*)(gcb + layer * 32 + oc0);
    float4 s4 = *(const float4*)(bng + layer * 32 + oc0);
    float4 b4 = *(const float4*)(bnb + layer * 32 + oc0);
    float sc0 = s4.x * rs, sc1 = s4.y * rs, sc2 = s4.z * rs, sc3 = s4.w * rs;
#pragma unroll
    for (int hh = 0; hh < 2; hh++)
#pragma unroll
      for (int wt = 0; wt < 4; wt++) {
        u16* hp = hbase + (long)(hh * 64 + wt * 16 + r) * 32 + oc0;
        ushort4 rv = *(const ushort4*)hp;
        f32x4 a = acc2[hh][wt][oct];
        ushort4 ov;
        ov.x = f2b((a[0] + g4.x + b2f(rv.x)) * sc0 + b4.x);
        ov.y = f2b((a[1] + g4.y + b2f(rv.y)) * sc1 + b4.y);
        ov.z = f2b((a[2] + g4.z + b2f(rv.z)) * sc2 + b4.z);
        ov.w = f2b((a[3] + g4.w + b2f(rv.w)) * sc3 + b4.w);
        *(ushort4*)hp = ov;
      }
  }
}

// ---------------- final 12-wide conv, split-K x4 + LDS reduce: out fp32 ----------------
__global__ __launch_bounds__(256) void k_e3(const u16* __restrict__ e1, const float* __restrict__ w2,
                                            const float* __restrict__ b2, float* __restrict__ out, int b0) {
  __shared__ float red[256 * 13];
  int t = threadIdx.x;
  int r = t & 63, qq = t >> 6;
  long rowi = (long)blockIdx.x * 64 + r;
  const u16* rp = e1 + rowi * 512 + qq * 128;
  float acc[12];
#pragma unroll
  for (int o = 0; o < 12; o++) acc[o] = 0.f;
  for (int ec = 0; ec < 128; ec += 8) {
    bf16x8 raw = *(const bf16x8*)(rp + ec);
    float xv[8];
#pragma unroll
    for (int jj = 0; jj < 8; jj++) xv[jj] = b2f((u16)raw[jj]);
#pragma unroll
    for (int o = 0; o < 12; o++) {
      const float* w = w2 + o * 512 + qq * 128 + ec;
#pragma unroll
      for (int jj = 0; jj < 8; jj++) acc[o] += w[jj] * xv[jj];
    }
  }
#pragma unroll
  for (int o = 0; o < 12; o++) red[t * 13 + o] = acc[o];
  __syncthreads();
  if (t < 64) {
    long row = (long)blockIdx.x * 64 + t;
    int b = b0 + (int)(row >> 10), v = (int)(row & 1023);
#pragma unroll
    for (int o = 0; o < 12; o++) {
      float s = red[t * 13 + o] + red[(64 + t) * 13 + o] + red[(128 + t) * 13 + o] + red[(192 + t) * 13 + o];
      out[((long)b * 12 + o) * 1024 + v] = s + b2[o];
    }
  }
}

extern "C" void kernel_launch(void* const* d_in, const int* in_sizes, int n_in,
                              void* d_out, int out_size, void* d_ws, size_t ws_size,
                              hipStream_t stream) {
  const float* x = (const float*)d_in[0];
  const float* start_w = (const float*)d_in[1];
  const float* start_b = (const float*)d_in[2];
  const float* nv1 = (const float*)d_in[3];
  const float* nv2 = (const float*)d_in[4];
  const float* filter_w = (const float*)d_in[5];
  const float* filter_b = (const float*)d_in[6];
  const float* gate_w = (const float*)d_in[7];
  const float* gate_b = (const float*)d_in[8];
  const float* skip_w = (const float*)d_in[9];
  const float* skip_b = (const float*)d_in[10];
  const float* gc_w = (const float*)d_in[11];
  const float* gc_b = (const float*)d_in[12];
  const float* bn_g = (const float*)d_in[13];
  const float* bn_b = (const float*)d_in[14];
  const float* end1_w = (const float*)d_in[15];
  const float* end1_b = (const float*)d_in[16];
  const float* end2_w = (const float*)d_in[17];
  const float* end2_b = (const float*)d_in[18];
  float* out = (float*)d_out;

  char* ws = (char*)d_ws;
  // ---- fixed region ----
  u16* adp = (u16*)(ws + 0);                  //  2,097,152
  u16* bcatT = (u16*)(ws + 2097152ull);       //  4,194,304 (granule-major [k/8][n][8])
  u16* wcat = (u16*)(ws + 6291456ull);        //    131,072
  u16* e1bf = (u16*)(ws + 6422528ull);        //    262,144
  float* sbias = (float*)(ws + 6684672ull);   //      1,024
  u16* fwgB = (u16*)(ws + 6685696ull);        //     65,536
  u16* gcwB = (u16*)(ws + 6751232ull);        //     49,152
  const size_t o_dyn = 6800384ull;

  // ---- adaptive batch chunking: per-batch dyn = 2,162,688 B (h+hg+hlast) ----
  int BCH = 16;
  {
    const int cand[5] = {64, 48, 32, 24, 16};
    for (int ci = 0; ci < 5; ci++) {
      size_t need = o_dyn + (size_t)cand[ci] * 2162688ull;
      if (need <= ws_size) { BCH = cand[ci]; break; }
    }
  }
  u16* h = (u16*)(ws + o_dyn);                                 // BCH*851,968  (b,13,v,c)
  u16* hg = (u16*)(ws + o_dyn + (size_t)BCH * 851968ull);      // BCH*786,432  (b,l,c,v)
  u16* hlast = (u16*)(ws + o_dyn + (size_t)BCH * 1638400ull);  // BCH*524,288
  // pre-loop temps (in h region, dead before k_start):
  u16* adpT_p = (u16*)(ws + o_dyn);
  u16* adp2T_p = (u16*)(ws + o_dyn + 2097152ull);
  // end-phase aliases (h/hg dead then)
  u16* e1c = (u16*)(ws + o_dyn);
  u16* srelu = (u16*)(ws + o_dyn + (size_t)BCH * 1048576ull);

  static const int dilA[8] = {1, 2, 1, 2, 1, 2, 1, 2};
  static const int offA[8] = {0, 1, 3, 4, 6, 7, 9, 10};

  k_wprep<<<992, 256, 0, stream>>>(skip_w, skip_b, end1_w, filter_w, gate_w, gc_w,
                                   wcat, e1bf, sbias, fwgB, gcwB);
  k_adp<<<1024, 256, 0, stream>>>(nv1, nv2, adp);
  k_transpose<<<dim3(16, 16), 256, 0, stream>>>(adp, adpT_p);
  k_gemm<<<dim3(8, 8), 256, 0, stream>>>(adpT_p, adp, adp2T_p, 1024, 1024, 1024, nullptr, 0);
  k_pack<<<2048, 256, 0, stream>>>(adpT_p, adp2T_p, bcatT);

  for (int b0 = 0; b0 < 64; b0 += BCH) {
    int bc = (64 - b0 < BCH) ? (64 - b0) : BCH;
    k_start<<<dim3(16, bc), 256, 0, stream>>>(x, start_w, start_b, h, b0);
    for (int i = 0; i < 8; i++) {
      int d = dilA[i], off = offA[i], Lo = 13 - off - d;
      k_gate<<<dim3(4, Lo, bc), 256, 0, stream>>>(h, hg, hlast, fwgB, filter_b, gate_b,
                                                  Lo, d, off, i, (i < 7) ? 1 : 0);
      if (i < 7) {
        k_xgc<<<dim3(bc * Lo / 4, 8), 256, 0, stream>>>(hg, bcatT, h, gcwB, gc_b,
                                                        bn_g, bn_b, Lo, d, off, i);
      }
    }
    int Mc = bc * 1024;
    k_gemm<<<dim3(2, Mc / 128), 256, 0, stream>>>(hlast, wcat, srelu, Mc, 256, 256, sbias, 1);
    k_gemm<<<dim3(4, Mc / 128), 256, 0, stream>>>(srelu, e1bf, e1c, Mc, 512, 256, end1_b, 1);
    k_e3<<<bc * 16, 256, 0, stream>>>(e1c, end2_w, end2_b, out, b0);
  }
  (void)in_sizes; (void)n_in; (void)out_size;
}

// Round 10
// 874.795 us; speedup vs baseline: 5.8545x; 5.8545x over previous
//
#include <hip/hip_runtime.h>

typedef unsigned short u16;
typedef unsigned int u32;
typedef __attribute__((ext_vector_type(8))) short bf16x8;
typedef __attribute__((ext_vector_type(4))) float f32x4;

__device__ __forceinline__ float b2f(u16 u) { return __uint_as_float(((u32)u) << 16); }
__device__ __forceinline__ u16 f2b(float f) {
  u32 u = __float_as_uint(f);
  return (u16)((u + 0x7FFFu + ((u >> 16) & 1u)) >> 16);
}

__device__ __forceinline__ void gld_lds16(const void* g, void* l) {
  __builtin_amdgcn_global_load_lds((const __attribute__((address_space(1))) u32*)g,
                                   (__attribute__((address_space(3))) u32*)l, 16, 0, 0);
}

// ---------------- adp = softmax(relu(nv1@nv2), axis=1), bf16, row-major (v,w) ----------------
__global__ __launch_bounds__(256) void k_adp(const float* __restrict__ nv1,
                                             const float* __restrict__ nv2,
                                             u16* __restrict__ adp) {
  int v = blockIdx.x, t = threadIdx.x;
  __shared__ float red[8];
  const float* nrow = nv1 + v * 10;
  float z[4];
#pragma unroll
  for (int j = 0; j < 4; j++) {
    int w = t + j * 256;
    float s = 0.f;
#pragma unroll
    for (int a = 0; a < 10; a++) s += nrow[a] * nv2[a * 1024 + w];
    z[j] = fmaxf(s, 0.f);
  }
  float m = fmaxf(fmaxf(z[0], z[1]), fmaxf(z[2], z[3]));
  for (int off = 32; off; off >>= 1) m = fmaxf(m, __shfl_down(m, off));
  if ((t & 63) == 0) red[t >> 6] = m;
  __syncthreads();
  m = fmaxf(fmaxf(red[0], red[1]), fmaxf(red[2], red[3]));
  float e[4], s = 0.f;
#pragma unroll
  for (int j = 0; j < 4; j++) { e[j] = __expf(z[j] - m); s += e[j]; }
  for (int off = 32; off; off >>= 1) s += __shfl_down(s, off);
  if ((t & 63) == 0) red[4 + (t >> 6)] = s;
  __syncthreads();
  s = red[4] + red[5] + red[6] + red[7];
  float inv = 1.0f / s;
#pragma unroll
  for (int j = 0; j < 4; j++) adp[(long)v * 1024 + t + j * 256] = f2b(e[j] * inv);
}

// ---------------- transpose 1024x1024 bf16 ----------------
__global__ __launch_bounds__(256) void k_transpose(const u16* __restrict__ in, u16* __restrict__ out) {
  __shared__ u16 tile[64 * 65];
  int w0 = blockIdx.x * 64, v0 = blockIdx.y * 64, t = threadIdx.x;
  int c = t & 63, r4 = t >> 6;
  for (int rr = r4; rr < 64; rr += 4) tile[rr * 65 + c] = in[(long)(v0 + rr) * 1024 + w0 + c];
  __syncthreads();
  for (int rr = r4; rr < 64; rr += 4) out[(long)(w0 + rr) * 1024 + v0 + c] = tile[c * 65 + rr];
}

// ---------------- pack bcatT: [k/8][n][8] granule-major for coalesced B-fragment loads ----------
// n = (v>>6)*128 + src*64 + (v&63); K-granule order preserved -> bit-identical accumulation.
__global__ __launch_bounds__(256) void k_pack(const u16* __restrict__ adpT, const u16* __restrict__ adp2T,
                                              u16* __restrict__ bcatT) {
  int n = blockIdx.x;
  int g = n >> 7, rem = n & 127, src = rem >> 6, v = g * 64 + (rem & 63);
  const u16* s = (src ? adp2T : adpT) + (long)v * 1024;
  int t = threadIdx.x;
  ushort4 val = ((const ushort4*)s)[t];
  *(ushort4*)(bcatT + (long)(t >> 1) * 16384 + n * 8 + (t & 1) * 4) = val;
}

// ---------------- weight repacks + summed skip bias ----------------
__global__ __launch_bounds__(256) void k_wprep(const float* __restrict__ skw, const float* __restrict__ skb,
                                               const float* __restrict__ e1w,
                                               const float* __restrict__ fw, const float* __restrict__ gw,
                                               const float* __restrict__ gcw,
                                               u16* __restrict__ wcat, u16* __restrict__ e1bf,
                                               float* __restrict__ sbias,
                                               u16* __restrict__ fwgB, u16* __restrict__ gcwB) {
  int idx = blockIdx.x * 256 + threadIdx.x;
  if (idx < 65536) {
    int cp = idx >> 8, k = idx & 255, i = k >> 5, c = k & 31;
    wcat[idx] = f2b(skw[(i * 256 + cp) * 32 + c]);
  } else if (idx < 196608) {
    int j = idx - 65536;
    e1bf[j] = f2b(e1w[j]);
  } else if (idx < 229376) {
    int j = idx - 196608;
    int layer = j >> 12, rem = j & 4095, n = rem >> 6, k = rem & 63;
    int tap = k >> 5, ci = k & 31, oc = n & 31;
    const float* src = (n < 32) ? fw : gw;
    fwgB[j] = f2b(src[((layer * 32 + oc) * 32 + ci) * 2 + tap]);
  } else if (idx < 253952) {
    int j = idx - 229376;  // native-order bf16 copy of gc_w
    gcwB[j] = f2b(gcw[j]);
  }
  if (idx < 256) {
    float s = 0.f;
    for (int i = 0; i < 8; i++) s += skb[i * 256 + idx];
    sbias[idx] = s;
  }
}

// ---------------- start conv: h[b][slot][v][c] bf16 ----------------
__global__ __launch_bounds__(256) void k_start(const float* __restrict__ x, const float* __restrict__ sw,
                                               const float* __restrict__ sb, u16* __restrict__ h, int b0) {
  int bl = blockIdx.y, bg = b0 + bl, v0 = blockIdx.x * 64, t = threadIdx.x;
  __shared__ float xs[2 * 832];  // [i][vl*13+l]
  for (int idx = t; idx < 2 * 832; idx += 256) {
    int i = idx / 832, rem = idx % 832;
    xs[idx] = x[((long)(bg * 2 + i) * 1024 + v0) * 13 + rem];
  }
  __syncthreads();
  for (int p = t; p < 832; p += 256) {
    int l = p % 13, vl = p / 13;
    float x0 = xs[vl * 13 + l];
    float x1 = xs[832 + vl * 13 + l];
    u16* dst = h + ((long)(bl * 13 + l) * 1024 + v0 + vl) * 32;
#pragma unroll
    for (int cq = 0; cq < 4; cq++) {
      bf16x8 pk;
#pragma unroll
      for (int j = 0; j < 8; j++) {
        int c = cq * 8 + j;
        pk[j] = (short)f2b(sw[c * 2 + 0] * x0 + sw[c * 2 + 1] * x1 + sb[c]);
      }
      *(bf16x8*)(dst + cq * 8) = pk;
    }
  }
}

// ---------------- gated dilated conv via MFMA: M=v, N=64 (f|g), K=64 (2 taps x 32 ci) ----------
__global__ __launch_bounds__(256, 2) void k_gate(const u16* __restrict__ h, u16* __restrict__ hg,
                                                 u16* __restrict__ hlast,
                                                 const u16* __restrict__ fwgB,
                                                 const float* __restrict__ fb, const float* __restrict__ gb,
                                                 int Lo, int d, int off, int layer, int writehg) {
  int t = threadIdx.x, wave = t >> 6, lane = t & 63;
  int q = lane >> 4, r = lane & 15;
  int b = blockIdx.z, l = blockIdx.y;
  int vbase = blockIdx.x * 256 + wave * 64;
  f32x4 acc[4][4] = {};
  const u16* wb = fwgB + layer * 4096;
#pragma unroll
  for (int ks = 0; ks < 2; ks++) {
    const u16* hrow = h + ((long)(b * 13 + off + l + ks * d) * 1024) * 32;
    bf16x8 af[4], bf[4];
#pragma unroll
    for (int mt = 0; mt < 4; mt++)
      af[mt] = *(const bf16x8*)(hrow + (long)(vbase + mt * 16 + r) * 32 + q * 8);
#pragma unroll
    for (int nt = 0; nt < 4; nt++)
      bf[nt] = *(const bf16x8*)(wb + (nt * 16 + r) * 64 + ks * 32 + q * 8);
#pragma unroll
    for (int mt = 0; mt < 4; mt++)
#pragma unroll
      for (int nt = 0; nt < 4; nt++)
        acc[mt][nt] = __builtin_amdgcn_mfma_f32_16x16x32_bf16(af[mt], bf[nt], acc[mt][nt], 0, 0, 0);
  }
  int last = (l == Lo - 1);
#pragma unroll
  for (int nt = 0; nt < 2; nt++) {
    int oc = nt * 16 + r;
    float fbv = fb[layer * 32 + oc], gbv = gb[layer * 32 + oc];
#pragma unroll
    for (int mt = 0; mt < 4; mt++) {
      u16 vv[4];
#pragma unroll
      for (int rg = 0; rg < 4; rg++) {
        float f = acc[mt][nt][rg] + fbv;
        float g = acc[mt][nt + 2][rg] + gbv;
        float ft = 2.f * __builtin_amdgcn_rcpf(1.f + __expf(-2.f * f)) - 1.f;
        float sg = __builtin_amdgcn_rcpf(1.f + __expf(-g));
        vv[rg] = f2b(ft * sg);
      }
      int v0 = vbase + mt * 16 + q * 4;
      if (writehg) {
        ushort4 pk; pk.x = vv[0]; pk.y = vv[1]; pk.z = vv[2]; pk.w = vv[3];
        *(ushort4*)(hg + ((long)(b * Lo + l) * 32 + oc) * 1024 + v0) = pk;
      }
      if (last) {
#pragma unroll
        for (int rg = 0; rg < 4; rg++)
          hlast[((long)(b * 1024 + v0 + rg)) * 256 + layer * 32 + oc] = vv[rg];
      }
    }
  }
}

// ---------------- generic GEMM (m97 structure), used for adp2 + end-head ----------------
__global__ __launch_bounds__(256) void k_gemm(const u16* __restrict__ A, const u16* __restrict__ Bt,
                                              u16* __restrict__ C, int M, int N, int K,
                                              const float* __restrict__ bias, int relu) {
  __shared__ __align__(16) u16 As[128 * 32];
  __shared__ __align__(16) u16 Bs[128 * 32];
  int t = threadIdx.x, wave = t >> 6, lane = t & 63;
  int m0 = blockIdx.y * 128, n0 = blockIdx.x * 128;
  int wr = (wave >> 1) * 64, wc = (wave & 1) * 64;
  int q = lane >> 4, r = lane & 15;
  f32x4 acc[4][4] = {};
  const u16* Ag = A + (long)(m0 + wave * 32 + (lane >> 2)) * K + (lane & 3) * 8;
  const u16* Bg = Bt + (long)(n0 + wave * 32 + (lane >> 2)) * K + (lane & 3) * 8;
  u16* Al = As + wave * 1024 + lane * 8;
  u16* Bl = Bs + wave * 1024 + lane * 8;
  for (int k0 = 0; k0 < K; k0 += 32) {
    __syncthreads();
    gld_lds16(Ag + k0, Al);
    gld_lds16(Ag + 16 * K + k0, Al + 512);
    gld_lds16(Bg + k0, Bl);
    gld_lds16(Bg + 16 * K + k0, Bl + 512);
    __syncthreads();
    bf16x8 af[4], bfr[4];
#pragma unroll
    for (int i = 0; i < 4; i++) {
      af[i] = *(const bf16x8*)(As + (wr + i * 16 + r) * 32 + q * 8);
      bfr[i] = *(const bf16x8*)(Bs + (wc + i * 16 + r) * 32 + q * 8);
    }
#pragma unroll
    for (int i = 0; i < 4; i++)
#pragma unroll
      for (int j = 0; j < 4; j++)
        acc[i][j] = __builtin_amdgcn_mfma_f32_16x16x32_bf16(af[i], bfr[j], acc[i][j], 0, 0, 0);
  }
#pragma unroll
  for (int i = 0; i < 4; i++) {
    int row = m0 + wr + i * 16 + q * 4;
#pragma unroll
    for (int j = 0; j < 4; j++) {
      int col = n0 + wc + j * 16 + r;
      float bv = bias ? bias[col] : 0.f;
#pragma unroll
      for (int rg = 0; rg < 4; rg++) {
        float vv = acc[i][j][rg] + bv;
        if (relu) vv = fmaxf(vv, 0.f);
        C[(long)(row + rg) * N + col] = f2b(vv);
      }
    }
  }
}

// ---------------- FUSED xgc v6 (REVERT; best measured: 881.86us total, k_xgc 110us) ----------
// v8 post-mortem: __launch_bounds__(256,4) forced a 128-reg cap < ~220 needed -> compiler
// allocated 64 VGPR + spilled acc to scratch (hbm_bytes 25x, MfmaUtil 3.5%, 11x slower).
// k_xgc occupancy is structurally register-bound at 2 waves/SIMD (acc[8][4]=128 regs/wave).
// v6 = BM128 x BN256, 4 waves, BK32, 2 blocks/CU, B direct from L2 (bcatT granule-major),
// A LDS-staged with XOR swizzle (source-side pre-swizzle, linear gld_lds dest; read
// qs = q^((r>>1)&3)) -> conflict-free b128. MfmaUtil 42% = instruction-demand/duration at
// this occupancy (1536 blocks x 1024 MFMA / 1024 SIMD / 264k cy) — further gains need a
// per-wave-tile shrink (epilogue remap), not schedule tuning (6 variants bracketed).
#define PADX 136
__global__ __launch_bounds__(256, 2) void k_xgc(const u16* __restrict__ hg, const u16* __restrict__ bcatT,
                                                u16* __restrict__ h,
                                                const u16* __restrict__ gcwB, const float* __restrict__ gcb,
                                                const float* __restrict__ bng, const float* __restrict__ bnb,
                                                int Lo, int d, int off, int layer) {
  // loop: A dbuf [2][128][32] u16 @ [0, 8192)
  // epilogue overlay: hgT 4*5120 = [0, 20480); xcs [256][136] = [0, 34816)
  __shared__ __align__(16) u16 smem[34816];
  int t = threadIdx.x, wave = t >> 6, lane = t & 63;
  int q = lane >> 4, r = lane & 15;
  // ---- block-ID remap: super-tile of 8 m-blocks x 8 n-groups -> 2MB A panel L2-resident ----
  int X = gridDim.x;
  int mblk, g;
  if ((X & 7) == 0) {
    int lin = blockIdx.x + X * blockIdx.y;
    mblk = (lin >> 6) * 8 + (lin & 7);
    g = (lin >> 3) & 7;
  } else {
    mblk = blockIdx.x;
    g = blockIdx.y;
  }
  int m0 = mblk * 128, n0 = g * 256;
  // A staging: source granule pre-swizzled (dest linear) so LDS(row,qs) holds granule qs^((row>>1)&3)
  const u16* AgS = hg + (long)(m0 + wave * 32 + (lane >> 2)) * 1024 +
                   (((lane & 3) ^ ((lane >> 3) & 3)) * 8);
  u16* Al = smem + wave * 1024 + lane * 8;
  // B direct: bcatT[(kg)*2048*8 + n*8]; wave n-range = n0 + wave*64
  const u16* BgW = bcatT + (long)(n0 + wave * 64 + r) * 8;
  int qs = (q ^ ((r >> 1) & 3)) * 8;  // swizzled read granule offset (u16)

#define STGA(BUF, K0)                              \
  gld_lds16(AgS + (K0), Al + (BUF) * 4096);        \
  gld_lds16(AgS + 16 * 1024 + (K0), Al + (BUF) * 4096 + 512);

#define LDB(DST, KG)                                                                   \
  _Pragma("unroll") for (int nt = 0; nt < 4; nt++)                                     \
      DST[nt] = *(const bf16x8*)(BgW + ((long)((KG) + q)) * 16384 + nt * 128);

#define MMS(BUF, BF)                                                                   \
  {                                                                                    \
    const u16* Ab = smem + (BUF) * 4096;                                               \
    __builtin_amdgcn_s_setprio(1);                                                     \
    _Pragma("unroll") for (int mt = 0; mt < 8; mt++) {                                 \
      bf16x8 a = *(const bf16x8*)(Ab + (mt * 16 + r) * 32 + qs);                       \
      _Pragma("unroll") for (int nt = 0; nt < 4; nt++)                                 \
          acc[mt][nt] = __builtin_amdgcn_mfma_f32_16x16x32_bf16(a, BF[nt],             \
                                                               acc[mt][nt], 0, 0, 0); \
    }                                                                                  \
    __builtin_amdgcn_s_setprio(0);                                                     \
  }

  f32x4 acc[8][4] = {};
  bf16x8 bA[4], bB[4];

  // prologue: stage A buf0 (k=0), load B k-step 0 into regs
  STGA(0, 0)
  LDB(bA, 0)
  __syncthreads();

#pragma unroll 1
  for (int ix = 0; ix < 16; ++ix) {
    int s1 = 2 * ix + 1, s2 = 2 * ix + 2;
    // even K-step 2ix: prefetch next B + stage buf1
    LDB(bB, s1 * 4)
    STGA(1, s1 * 32)
    MMS(0, bA)
    __syncthreads();
    // odd K-step 2ix+1
    if (s2 < 32) {
      LDB(bA, s2 * 4)
      STGA(0, s2 * 32)
    }
    MMS(1, bB)
    __syncthreads();
  }
#undef STGA
#undef LDB
#undef MMS
  // ---- phase A: stage hg tile transposed: hgT[bl 0..3][w 0..127][ci 0..31], row stride 40 ----
  {
    int row = t >> 1, half = t & 1;
    int bl_ = row >> 5, ci = row & 31;
    const u16* src = hg + (long)(m0 + row) * 1024 + g * 128 + half * 64;
    u16* dstb = smem + bl_ * 5120 + ci;
#pragma unroll
    for (int e = 0; e < 8; e++) {
      bf16x8 v8 = *(const bf16x8*)(src + e * 8);
#pragma unroll
      for (int jj = 0; jj < 8; jj++) dstb[(half * 64 + e * 8 + jj) * 40] = (u16)v8[jj];
    }
  }
  __syncthreads();
  bf16x8 miniA[2][4];
#pragma unroll
  for (int hh = 0; hh < 2; hh++)
#pragma unroll
    for (int wt = 0; wt < 4; wt++)
      miniA[hh][wt] = *(const bf16x8*)(smem + wave * 5120 + (hh * 64 + wt * 16 + r) * 40 + q * 8);
  __syncthreads();  // hgT dead
  // ---- phase B: acc -> xcs[n_local 0..255][m_local 0..127], stride PADX ----
#pragma unroll
  for (int i = 0; i < 8; i++) {
#pragma unroll
    for (int j = 0; j < 4; j++) {
      int row_m = i * 16 + q * 4;
      int col_n = wave * 64 + j * 16 + r;
      ushort4 pk;
      pk.x = f2b(acc[i][j][0]); pk.y = f2b(acc[i][j][1]);
      pk.z = f2b(acc[i][j][2]); pk.w = f2b(acc[i][j][3]);
      *(ushort4*)(smem + col_n * PADX + row_m) = pk;
    }
  }
  __syncthreads();
  // ---- mini-GEMM per wave (= bl group), OPERAND-SWAPPED: out[oc][w], K2=96 ----
  int blg = mblk * 4 + wave;
  int b = blg / Lo, l = blg % Lo;
  bf16x8 bf2[2][3];
#pragma unroll
  for (int oct = 0; oct < 2; oct++)
#pragma unroll
    for (int ks = 0; ks < 3; ks++)
      bf2[oct][ks] = *(const bf16x8*)(gcwB + ((long)layer * 32 + oct * 16 + r) * 96 + ks * 32 + q * 8);
  f32x4 acc2[2][4][2] = {};  // [hh][wt][oct]; lane: oc = oct*16+q*4+rg, w = hh*64+wt*16+r
#pragma unroll
  for (int hh = 0; hh < 2; hh++)
#pragma unroll
    for (int wt = 0; wt < 4; wt++) {
#pragma unroll
      for (int oct = 0; oct < 2; oct++)
        acc2[hh][wt][oct] = __builtin_amdgcn_mfma_f32_16x16x32_bf16(bf2[oct][0], miniA[hh][wt],
                                                                    acc2[hh][wt][oct], 0, 0, 0);
#pragma unroll
      for (int ks = 1; ks < 3; ks++) {
        bf16x8 a2 = *(const bf16x8*)(smem + (hh * 128 + (ks - 1) * 64 + wt * 16 + r) * PADX +
                                     wave * 32 + q * 8);
#pragma unroll
        for (int oct = 0; oct < 2; oct++)
          acc2[hh][wt][oct] = __builtin_amdgcn_mfma_f32_16x16x32_bf16(bf2[oct][ks], a2,
                                                                      acc2[hh][wt][oct], 0, 0, 0);
      }
    }
  // ---- epilogue: + gcb, residual, BN, in-place h write — ushort4 RMW (4 oc per lane) ----
  const float rs = rsqrtf(1.f + 1e-5f);
  u16* hbase = h + ((long)(b * 13 + off + l + d) * 1024 + g * 128) * 32;
#pragma unroll
  for (int oct = 0; oct < 2; oct++) {
    int oc0 = oct * 16 + q * 4;
    float4 g4 = *(const float4*)(gcb + layer * 32 + oc0);
    float4 s4 = *(const float4*)(bng + layer * 32 + oc0);
    float4 b4 = *(const float4*)(bnb + layer * 32 + oc0);
    float sc0 = s4.x * rs, sc1 = s4.y * rs, sc2 = s4.z * rs, sc3 = s4.w * rs;
#pragma unroll
    for (int hh = 0; hh < 2; hh++)
#pragma unroll
      for (int wt = 0; wt < 4; wt++) {
        u16* hp = hbase + (long)(hh * 64 + wt * 16 + r) * 32 + oc0;
        ushort4 rv = *(const ushort4*)hp;
        f32x4 a = acc2[hh][wt][oct];
        ushort4 ov;
        ov.x = f2b((a[0] + g4.x + b2f(rv.x)) * sc0 + b4.x);
        ov.y = f2b((a[1] + g4.y + b2f(rv.y)) * sc1 + b4.y);
        ov.z = f2b((a[2] + g4.z + b2f(rv.z)) * sc2 + b4.z);
        ov.w = f2b((a[3] + g4.w + b2f(rv.w)) * sc3 + b4.w);
        *(ushort4*)hp = ov;
      }
  }
}

// ---------------- final 12-wide conv, split-K x4 + LDS reduce: out fp32 ----------------
__global__ __launch_bounds__(256) void k_e3(const u16* __restrict__ e1, const float* __restrict__ w2,
                                            const float* __restrict__ b2, float* __restrict__ out, int b0) {
  __shared__ float red[256 * 13];
  int t = threadIdx.x;
  int r = t & 63, qq = t >> 6;
  long rowi = (long)blockIdx.x * 64 + r;
  const u16* rp = e1 + rowi * 512 + qq * 128;
  float acc[12];
#pragma unroll
  for (int o = 0; o < 12; o++) acc[o] = 0.f;
  for (int ec = 0; ec < 128; ec += 8) {
    bf16x8 raw = *(const bf16x8*)(rp + ec);
    float xv[8];
#pragma unroll
    for (int jj = 0; jj < 8; jj++) xv[jj] = b2f((u16)raw[jj]);
#pragma unroll
    for (int o = 0; o < 12; o++) {
      const float* w = w2 + o * 512 + qq * 128 + ec;
#pragma unroll
      for (int jj = 0; jj < 8; jj++) acc[o] += w[jj] * xv[jj];
    }
  }
#pragma unroll
  for (int o = 0; o < 12; o++) red[t * 13 + o] = acc[o];
  __syncthreads();
  if (t < 64) {
    long row = (long)blockIdx.x * 64 + t;
    int b = b0 + (int)(row >> 10), v = (int)(row & 1023);
#pragma unroll
    for (int o = 0; o < 12; o++) {
      float s = red[t * 13 + o] + red[(64 + t) * 13 + o] + red[(128 + t) * 13 + o] + red[(192 + t) * 13 + o];
      out[((long)b * 12 + o) * 1024 + v] = s + b2[o];
    }
  }
}

extern "C" void kernel_launch(void* const* d_in, const int* in_sizes, int n_in,
                              void* d_out, int out_size, void* d_ws, size_t ws_size,
                              hipStream_t stream) {
  const float* x = (const float*)d_in[0];
  const float* start_w = (const float*)d_in[1];
  const float* start_b = (const float*)d_in[2];
  const float* nv1 = (const float*)d_in[3];
  const float* nv2 = (const float*)d_in[4];
  const float* filter_w = (const float*)d_in[5];
  const float* filter_b = (const float*)d_in[6];
  const float* gate_w = (const float*)d_in[7];
  const float* gate_b = (const float*)d_in[8];
  const float* skip_w = (const float*)d_in[9];
  const float* skip_b = (const float*)d_in[10];
  const float* gc_w = (const float*)d_in[11];
  const float* gc_b = (const float*)d_in[12];
  const float* bn_g = (const float*)d_in[13];
  const float* bn_b = (const float*)d_in[14];
  const float* end1_w = (const float*)d_in[15];
  const float* end1_b = (const float*)d_in[16];
  const float* end2_w = (const float*)d_in[17];
  const float* end2_b = (const float*)d_in[18];
  float* out = (float*)d_out;

  char* ws = (char*)d_ws;
  // ---- fixed region ----
  u16* adp = (u16*)(ws + 0);                  //  2,097,152
  u16* bcatT = (u16*)(ws + 2097152ull);       //  4,194,304 (granule-major [k/8][n][8])
  u16* wcat = (u16*)(ws + 6291456ull);        //    131,072
  u16* e1bf = (u16*)(ws + 6422528ull);        //    262,144
  float* sbias = (float*)(ws + 6684672ull);   //      1,024
  u16* fwgB = (u16*)(ws + 6685696ull);        //     65,536
  u16* gcwB = (u16*)(ws + 6751232ull);        //     49,152
  const size_t o_dyn = 6800384ull;

  // ---- adaptive batch chunking: per-batch dyn = 2,162,688 B (h+hg+hlast) ----
  int BCH = 16;
  {
    const int cand[5] = {64, 48, 32, 24, 16};
    for (int ci = 0; ci < 5; ci++) {
      size_t need = o_dyn + (size_t)cand[ci] * 2162688ull;
      if (need <= ws_size) { BCH = cand[ci]; break; }
    }
  }
  u16* h = (u16*)(ws + o_dyn);                                 // BCH*851,968  (b,13,v,c)
  u16* hg = (u16*)(ws + o_dyn + (size_t)BCH * 851968ull);      // BCH*786,432  (b,l,c,v)
  u16* hlast = (u16*)(ws + o_dyn + (size_t)BCH * 1638400ull);  // BCH*524,288
  // pre-loop temps (in h region, dead before k_start):
  u16* adpT_p = (u16*)(ws + o_dyn);
  u16* adp2T_p = (u16*)(ws + o_dyn + 2097152ull);
  // end-phase aliases (h/hg dead then)
  u16* e1c = (u16*)(ws + o_dyn);
  u16* srelu = (u16*)(ws + o_dyn + (size_t)BCH * 1048576ull);

  static const int dilA[8] = {1, 2, 1, 2, 1, 2, 1, 2};
  static const int offA[8] = {0, 1, 3, 4, 6, 7, 9, 10};

  k_wprep<<<992, 256, 0, stream>>>(skip_w, skip_b, end1_w, filter_w, gate_w, gc_w,
                                   wcat, e1bf, sbias, fwgB, gcwB);
  k_adp<<<1024, 256, 0, stream>>>(nv1, nv2, adp);
  k_transpose<<<dim3(16, 16), 256, 0, stream>>>(adp, adpT_p);
  k_gemm<<<dim3(8, 8), 256, 0, stream>>>(adpT_p, adp, adp2T_p, 1024, 1024, 1024, nullptr, 0);
  k_pack<<<2048, 256, 0, stream>>>(adpT_p, adp2T_p, bcatT);

  for (int b0 = 0; b0 < 64; b0 += BCH) {
    int bc = (64 - b0 < BCH) ? (64 - b0) : BCH;
    k_start<<<dim3(16, bc), 256, 0, stream>>>(x, start_w, start_b, h, b0);
    for (int i = 0; i < 8; i++) {
      int d = dilA[i], off = offA[i], Lo = 13 - off - d;
      k_gate<<<dim3(4, Lo, bc), 256, 0, stream>>>(h, hg, hlast, fwgB, filter_b, gate_b,
                                                  Lo, d, off, i, (i < 7) ? 1 : 0);
      if (i < 7) {
        k_xgc<<<dim3(bc * Lo / 4, 8), 256, 0, stream>>>(hg, bcatT, h, gcwB, gc_b,
                                                        bn_g, bn_b, Lo, d, off, i);
      }
    }
    int Mc = bc * 1024;
    k_gemm<<<dim3(2, Mc / 128), 256, 0, stream>>>(hlast, wcat, srelu, Mc, 256, 256, sbias, 1);
    k_gemm<<<dim3(4, Mc / 128), 256, 0, stream>>>(srelu, e1bf, e1c, Mc, 512, 256, end1_b, 1);
    k_e3<<<bc * 16, 256, 0, stream>>>(e1c, end2_w, end2_b, out, b0);
  }
  (void)in_sizes; (void)n_in; (void)out_size;
}